// Round 5
// baseline (74341.010 us; speedup 1.0000x reference)
//
#include <hip/hip_runtime.h>
#include <stdint.h>

// SpikingNetwork B=128 T=128 I=1024 dims 2048/2048/1024, beta=0.9, thr=1.0.
// R9: R5's proven topology (512 blk x 256 thr, 64m x 32n tiles, 4m x 2n/thr,
// L0 self-contained K=1024, L1/L2 ksplit2, R5 flags/partials/LIF verbatim)
// + latency-hiding chunk pipeline WITHOUT register pressure:
//   - B staged via global_load_lds (zero data VGPRs). lB[8 grp][4x64k + 8 pad]:
//     linear 1024B per wave-issue (gload_lds constraint); pad -> 2-way (free)
//     read conflicts; each wave stages the 2 groups it reads.
//   - A: group0 ra[4] (16 VGPR), groups1/2 rw[4] (4 VGPR) only.
//   - chunk 64k, LDS dbuf, ONE plain __syncthreads per chunk. Loads for ch+1
//     issued at top of ch; FMA (~1024cy) hides latency; syncthreads' vmcnt(0)
//     drain is then ~free. No inline asm, no raw barriers.
// DAG bit-identical to R5: ascending-k single-acc fmac chains (chunking does
// not alter order); owner merges ((P0+P1)+P2)+P3 with __fadd_rn.

#define TT   128
#define NB   128
#define DD2  1024

// ws layout (u32 units) — identical to R5
#define SPK0_OFF 0u
#define SPK1_OFF (128u*128u*64u)                 // 1,048,576
#define PART_OFF (2u*128u*128u*64u)              // 2,097,152
#define NHELP    192u
#define FLG_OFF  (PART_OFF + NHELP*4096u)        // 2,883,584
#define NFLG     1536u                           // pflag512 oflag512 done0 2x128 done1 2x128
#define WS_NEED_BYTES ((size_t)(FLG_OFF + NFLG) * 4u)   // 11,540,480

__device__ __forceinline__ void wait_ge(uint32_t* p, uint32_t tgt){
  while (__hip_atomic_load(p, __ATOMIC_ACQUIRE, __HIP_MEMORY_SCOPE_AGENT) < tgt)
    __builtin_amdgcn_s_sleep(1);
}

// LDS column swizzle for lA: 4-float granules (b128-aligned); constant over a
// 4-aligned k-granule. Spreads staging stores and fma reads across banks.
__device__ __forceinline__ constexpr int fswz(int k){
  return (k & 16) | ((k ^ (k >> 3)) & 12);
}

typedef const float __attribute__((address_space(1))) gfloat;
typedef float       __attribute__((address_space(3))) sfloat;
__device__ __forceinline__ void gload_lds16(const float* g, float* l){
  __builtin_amdgcn_global_load_lds((gfloat*)g, (sfloat*)l, 16, 0, 0);
}

__global__ void sentinel_kernel(float* o){ o[0] = 42.0f; }   // ws-too-small marker

__global__ __launch_bounds__(256, 2) void snn_kernel(
    const float* __restrict__ x,
    const float* __restrict__ W0, const float* __restrict__ b0,
    const float* __restrict__ W1, const float* __restrict__ b1,
    const float* __restrict__ W2, const float* __restrict__ b2,
    float* __restrict__ out, uint32_t* __restrict__ ws)
{
  __shared__ __align__(16) float lA[2][64][68];   // [buf][k][m^swz], 34,816 B
  __shared__ __align__(16) float lB[2][8][264];   // [buf][grp][row*64+k, 8 pad], 16,896 B
  __shared__ uint32_t lBits[64];                  // one spike word per row

  const int tid  = threadIdx.x;
  const int tm   = tid & 15;      // m-group: rows tm*4 .. +3
  const int tn   = tid >> 4;      // n-group: cols tn*2 .. +1
  const int wav  = tid >> 6;
  const int lane = tid & 63;
  const int bid  = blockIdx.x;

  uint32_t* spikes0  = ws + SPK0_OFF;
  uint32_t* spikes1  = ws + SPK1_OFF;
  float*    partials = (float*)(ws + PART_OFF);   // [NHELP][4096]
  uint32_t* flg   = ws + FLG_OFF;
  uint32_t* pflag = flg;            // [512] helper(bid)->owner: partials for t ready
  uint32_t* oflag = flg + 512;      // [512] owner(bid)->helper: consumed through t
  uint32_t* done0 = flg + 1024;     // [2][128] per m-half, target 64
  uint32_t* done1 = flg + 1280;     // [2][128]

  int group, kp, tl, m0, n0, K, hslot;
  const float *Wl, *bl;
  const uint32_t* spkIn; uint32_t* spkOut;
  uint32_t *dIn, *dOut;
  if (bid < 128) {          // L0: out 128x2048, K=1024, both chains in-block
    group=0; kp=0; tl=bid;
    m0=(tl>>6)*64; n0=(tl&63)*32; K=1024; Wl=W0; bl=b0;
    spkIn=nullptr; spkOut=spikes0; dIn=nullptr; dOut=done0 + (m0>>6)*128; hslot=-1;
  } else if (bid < 384) {   // L1: out 128x2048, K=2048, ksplit2
    group=1; int rel=bid-128; kp=rel&1; tl=rel>>1;
    m0=(tl>>6)*64; n0=(tl&63)*32; K=2048; Wl=W1; bl=b1;
    spkIn=spikes0; spkOut=spikes1;
    dIn=done0 + (m0>>6)*128; dOut=done1 + (m0>>6)*128; hslot=tl;
  } else {                  // L2: out 128x1024, K=2048, ksplit2
    group=2; int rel=bid-384; kp=rel&1; tl=rel>>1;
    m0=(tl>>5)*64; n0=(tl&31)*32; K=2048; Wl=W2; bl=b2;
    spkIn=spikes1; spkOut=nullptr;
    dIn=done1 + (m0>>6)*128; dOut=nullptr; hslot=128+tl;
  }
  const bool owner = (kp == 0);
  const int  K0    = kp * 1024;

  const float bias0 = bl[n0 + tn*2 + 0];
  const float bias1 = bl[n0 + tn*2 + 1];

  float vst[4][2];
  #pragma unroll
  for (int r = 0; r < 4; ++r) { vst[r][0] = 0.f; vst[r][1] = 0.f; }

  // staging decompositions (loop-invariant)
  const int s_sub = tid >> 4;       // 0..15
  const int s_kq  = tid & 15;       // float4 index along 64-k chunk

  // B gload_lds: wave w stages (and later reads) groups 2w, 2w+1.
  const int bg0 = wav*2;
  const float* wbase = Wl + (size_t)(n0 + bg0*4 + (lane>>4))*K + (lane&15)*4;

  float4   ra[4];     // group 0: A chunk, 4 rows-of-16 x 4k  (16 VGPR)
  uint32_t rw[4];     // groups 1/2: 4 rows' spike words       (4 VGPR)

#define ISSUE(CH) do {                                                         \
    const int kb_ = K0 + (CH)*64;                                              \
    float* lb_ = &lB[(CH)&1][bg0][0];                                          \
    gload_lds16(wbase + kb_,               lb_);                               \
    gload_lds16(wbase + 4*(size_t)K + kb_, lb_ + 264);                         \
    if (group == 0) {                                                          \
      ra[0] = *(const float4*)(xb0 + kb_);                                     \
      ra[1] = *(const float4*)(xb1 + kb_);                                     \
      ra[2] = *(const float4*)(xb2 + kb_);                                     \
      ra[3] = *(const float4*)(xb3 + kb_);                                     \
    } else {                                                                   \
      const uint32_t* sp_ = sb + (kb_>>5);                                     \
      rw[0] = __hip_atomic_load(sp_,     __ATOMIC_RELAXED, __HIP_MEMORY_SCOPE_AGENT); \
      rw[1] = __hip_atomic_load(sp_+64,  __ATOMIC_RELAXED, __HIP_MEMORY_SCOPE_AGENT); \
      rw[2] = __hip_atomic_load(sp_+128, __ATOMIC_RELAXED, __HIP_MEMORY_SCOPE_AGENT); \
      rw[3] = __hip_atomic_load(sp_+192, __ATOMIC_RELAXED, __HIP_MEMORY_SCOPE_AGENT); \
    }                                                                          \
  } while (0)

#define WRITEA(BUF) do {                                                       \
    float (*cA_)[68] = lA[BUF];                                                \
    if (group == 0) {                                                          \
      const int k0_ = s_kq*4, sw_ = fswz(k0_);                                 \
      { const int col = (s_sub +  0) ^ sw_;                                    \
        cA_[k0_+0][col]=ra[0].x; cA_[k0_+1][col]=ra[0].y;                      \
        cA_[k0_+2][col]=ra[0].z; cA_[k0_+3][col]=ra[0].w; }                    \
      { const int col = (s_sub + 16) ^ sw_;                                    \
        cA_[k0_+0][col]=ra[1].x; cA_[k0_+1][col]=ra[1].y;                      \
        cA_[k0_+2][col]=ra[1].z; cA_[k0_+3][col]=ra[1].w; }                    \
      { const int col = (s_sub + 32) ^ sw_;                                    \
        cA_[k0_+0][col]=ra[2].x; cA_[k0_+1][col]=ra[2].y;                      \
        cA_[k0_+2][col]=ra[2].z; cA_[k0_+3][col]=ra[2].w; }                    \
      { const int col = (s_sub + 48) ^ sw_;                                    \
        cA_[k0_+0][col]=ra[3].x; cA_[k0_+1][col]=ra[3].y;                      \
        cA_[k0_+2][col]=ra[3].z; cA_[k0_+3][col]=ra[3].w; }                    \
    } else {                                                                   \
      _Pragma("unroll")                                                        \
      for (int i = 0; i < 4; ++i) {                                            \
        const int k_ = s_sub*4 + i;                                            \
        const int sh_ = k_ & 31;                                               \
        float4 f_;                                                             \
        f_.x = ((rw[0] >> sh_) & 1u) ? 1.0f : 0.0f;                            \
        f_.y = ((rw[1] >> sh_) & 1u) ? 1.0f : 0.0f;                            \
        f_.z = ((rw[2] >> sh_) & 1u) ? 1.0f : 0.0f;                            \
        f_.w = ((rw[3] >> sh_) & 1u) ? 1.0f : 0.0f;                            \
        *(float4*)&cA_[k_][(s_kq*4) ^ fswz(k_)] = f_;                          \
      }                                                                        \
    }                                                                          \
  } while (0)

#define FMA_CHUNK(BUF, P) do {                                                 \
    float (*cA_)[68] = lA[BUF];                                                \
    const float* pB_ = &lB[BUF][tn>>1][((tn&1)*2)*64];                         \
    _Pragma("unroll")                                                          \
    for (int k4 = 0; k4 < 16; ++k4) {                                          \
      const int kbase = k4*4;                                                  \
      const int sw = fswz(kbase);                                              \
      const float* pa = &cA_[kbase][(tm*4) ^ sw];                              \
      const float4 b0v = *(const float4*)(pB_ + kbase);                        \
      const float4 b1v = *(const float4*)(pB_ + 64 + kbase);                   \
      _Pragma("unroll")                                                        \
      for (int u = 0; u < 4; ++u) {                                            \
        const float4 a  = *(const float4*)(pa + u*68);                         \
        const float bv0 = (u==0) ? b0v.x : (u==1) ? b0v.y : (u==2) ? b0v.z : b0v.w; \
        const float bv1 = (u==0) ? b1v.x : (u==1) ? b1v.y : (u==2) ? b1v.z : b1v.w; \
        acc2[P][0][0] = __builtin_fmaf(a.x, bv0, acc2[P][0][0]);               \
        acc2[P][1][0] = __builtin_fmaf(a.y, bv0, acc2[P][1][0]);               \
        acc2[P][2][0] = __builtin_fmaf(a.z, bv0, acc2[P][2][0]);               \
        acc2[P][3][0] = __builtin_fmaf(a.w, bv0, acc2[P][3][0]);               \
        acc2[P][0][1] = __builtin_fmaf(a.x, bv1, acc2[P][0][1]);               \
        acc2[P][1][1] = __builtin_fmaf(a.y, bv1, acc2[P][1][1]);               \
        acc2[P][2][1] = __builtin_fmaf(a.z, bv1, acc2[P][2][1]);               \
        acc2[P][3][1] = __builtin_fmaf(a.w, bv1, acc2[P][3][1]);               \
      }                                                                        \
    }                                                                          \
  } while (0)

  for (int t = 0; t < TT; ++t) {
    if (dIn) {  // previous layer's spikes for this m-half must be complete
      if (tid == 0) wait_ge(&dIn[t], 64u);
      __syncthreads();
    }

    // per-t staging bases (pointers only computed; deref guarded by group)
    const float* xb0 = x + ((size_t)(m0 + s_sub +  0)*TT + t)*1024 + s_kq*4;
    const float* xb1 = x + ((size_t)(m0 + s_sub + 16)*TT + t)*1024 + s_kq*4;
    const float* xb2 = x + ((size_t)(m0 + s_sub + 32)*TT + t)*1024 + s_kq*4;
    const float* xb3 = x + ((size_t)(m0 + s_sub + 48)*TT + t)*1024 + s_kq*4;
    const uint32_t* sb = (group == 0) ? nullptr
        : spkIn + ((size_t)t*NB + m0 + s_kq*4)*64 + (s_sub>>3);

    float acc2[2][4][2];   // two 512-k partial chains
    #pragma unroll
    for (int p = 0; p < 2; ++p)
      #pragma unroll
      for (int r = 0; r < 4; ++r) { acc2[p][r][0] = 0.f; acc2[p][r][1] = 0.f; }

    // prologue: chunk 0 (only exposed staging latency per t)
    ISSUE(0);
    WRITEA(0);
    __syncthreads();   // drains vmcnt(0): gload_lds B(0) + ra/rw complete

    #pragma unroll
    for (int p = 0; p < 2; ++p) {
      #pragma unroll 1
      for (int c = 0; c < 8; ++c) {
        const int ch = p*8 + c;
        const int buf = ch & 1;
        const bool more = (p == 0) | (c < 7);
        if (more) ISSUE(ch+1);          // loads fly during FMA below
        FMA_CHUNK(buf, p);              // 512 FMA/thread, ~1024 cy window
        if (more) WRITEA(buf^1);        // ra/rw landed during FMA
        __syncthreads();                // vmcnt(0)+lgkmcnt(0): both ~drained
      }
    }

    if (!owner) {
      // single-buffered partials: wait until owner consumed t-1 before overwrite
      if (t >= 1) { if (tid == 0) wait_ge(&oflag[bid-1], (uint32_t)t); __syncthreads(); }
      uint64_t* pb = (uint64_t*)(partials + (size_t)hslot*4096) + tid*8;
      #pragma unroll
      for (int h = 0; h < 2; ++h)
        #pragma unroll
        for (int r = 0; r < 4; ++r) {
          union { float f[2]; uint64_t u; } cv;
          cv.f[0] = acc2[h][r][0]; cv.f[1] = acc2[h][r][1];
          __hip_atomic_store(&pb[h*4+r], cv.u, __ATOMIC_RELAXED, __HIP_MEMORY_SCOPE_AGENT);
        }
      __syncthreads();
      if (tid == 0) __hip_atomic_store(&pflag[bid], (uint32_t)(t+1), __ATOMIC_RELEASE, __HIP_MEMORY_SCOPE_AGENT);
      continue;
    }

    // owner: acc = (P0 + P1), then += P2, += P3 (ascending-k merge, DAG as R5)
    float acc[4][2];
    #pragma unroll
    for (int r = 0; r < 4; ++r) {
      acc[r][0] = __fadd_rn(acc2[0][r][0], acc2[1][r][0]);
      acc[r][1] = __fadd_rn(acc2[0][r][1], acc2[1][r][1]);
    }

    if (hslot >= 0) {   // L1/L2: fold in helper's P2 then P3
      if (tid == 0) wait_ge(&pflag[bid+1], (uint32_t)(t+1));
      __syncthreads();
      uint64_t* pb = (uint64_t*)(partials + (size_t)hslot*4096) + tid*8;
      #pragma unroll
      for (int h = 0; h < 2; ++h)
        #pragma unroll
        for (int r = 0; r < 4; ++r) {
          union { uint64_t u; float f[2]; } cv;
          cv.u = __hip_atomic_load(&pb[h*4+r], __ATOMIC_RELAXED, __HIP_MEMORY_SCOPE_AGENT);
          acc[r][0] = __fadd_rn(acc[r][0], cv.f[0]);
          acc[r][1] = __fadd_rn(acc[r][1], cv.f[1]);
        }
      __syncthreads();
      if (tid == 0) __hip_atomic_store(&oflag[bid], (uint32_t)(t+1), __ATOMIC_RELEASE, __HIP_MEMORY_SCOPE_AGENT);
    }

    if (group < 2) { if (tid < 64) lBits[tid] = 0; __syncthreads(); }

    // LIF: cur = acc + b (rn); v = 0.9*v + cur (mul+add rn, NO fma contraction);
    // spk = v > 1.0 strictly; v -= spk.
    float sv[4][2], vv8[4][2];
    #pragma unroll
    for (int r = 0; r < 4; ++r) {
      uint32_t msk = 0;
      #pragma unroll
      for (int c = 0; c < 2; ++c) {
        float cur = __fadd_rn(acc[r][c], c ? bias1 : bias0);
        float vv  = __fadd_rn(__fmul_rn(0.9f, vst[r][c]), cur);
        float s   = (vv > 1.0f) ? 1.0f : 0.0f;
        vv = __fsub_rn(vv, s);
        vst[r][c] = vv;
        sv[r][c] = s; vv8[r][c] = vv;
        msk |= (s != 0.f) ? (1u << (tn*2 + c)) : 0u;
      }
      if (group < 2 && msk) atomicOr(&lBits[tm*4 + r], msk);
    }

    if (group == 2) {
      #pragma unroll
      for (int r = 0; r < 4; ++r) {
        size_t o  = ((size_t)(m0 + tm*4 + r)*TT + t)*DD2 + n0 + tn*2;
        *(float2*)(out + o)  = make_float2(sv[r][0], sv[r][1]);
        size_t ov = (size_t)NB*TT*DD2 + o;
        *(float2*)(out + ov) = make_float2(vv8[r][0], vv8[r][1]);
      }
    } else {
      __syncthreads();
      if (tid < 64)
        __hip_atomic_store(&spkOut[((size_t)t*NB + m0 + tid)*64 + (n0>>5)],
                           lBits[tid], __ATOMIC_RELAXED, __HIP_MEMORY_SCOPE_AGENT);
      __syncthreads();
      if (tid == 0) __hip_atomic_fetch_add(&dOut[t], 1u, __ATOMIC_RELEASE, __HIP_MEMORY_SCOPE_AGENT);
    }
  }
#undef ISSUE
#undef WRITEA
#undef FMA_CHUNK
}

extern "C" void kernel_launch(void* const* d_in, const int* in_sizes, int n_in,
                              void* d_out, int out_size, void* d_ws, size_t ws_size,
                              hipStream_t stream) {
  (void)in_sizes; (void)n_in; (void)out_size;
  float* outf = (float*)d_out;
  if (ws_size < WS_NEED_BYTES) {            // diagnostic: absmax ~41 => ws too small
    sentinel_kernel<<<1, 1, 0, stream>>>(outf);
    return;
  }
  const float* x  = (const float*)d_in[0];
  const float* W0 = (const float*)d_in[1];
  const float* b0 = (const float*)d_in[2];
  const float* W1 = (const float*)d_in[3];
  const float* b1 = (const float*)d_in[4];
  const float* W2 = (const float*)d_in[5];
  const float* b2 = (const float*)d_in[6];
  uint32_t* ws = (uint32_t*)d_ws;

  // zero flags (spikes/partials are write-before-read; flags gate everything)
  hipMemsetAsync(ws + FLG_OFF, 0, NFLG * sizeof(uint32_t), stream);

  snn_kernel<<<512, 256, 0, stream>>>(x, W0, b0, W1, b1, W2, b2, outf, ws);
}

// Round 6
// 7060.603 us; speedup vs baseline: 10.5290x; 10.5290x over previous
//
#include <hip/hip_runtime.h>
#include <stdint.h>

// SpikingNetwork B=128 T=128 I=1024 dims 2048/2048/1024, beta=0.9, thr=1.0.
// R10: R5's proven per-half code (7.6ms) on merged 512-thread blocks.
// 256 blocks x 512 thr; halves (tid>>8) replace R5's owner/helper block pairs:
//   L0: 64 blocks, each half = independent full tile (64m x 32n, K=1024).
//   L1: 128 blocks, halves = k-split halves of one tile (K=2048).
//   L2: 64 blocks, same.
// k-split partials exchanged via LDS (helper's lA reused as buffer) under
// __syncthreads — NO global partials, NO pflag/oflag spins. Inter-layer
// spike bitmasks + done-counters unchanged (targets 32/64 producers).
// VGPR cap now 256 (launch_bounds(512,2), 1 blk/CU forced by 104KB LDS);
// R5 inner loops verbatim. DAG bit-identical: ascending-k fmac chains,
// owner merges ((P0+P1)+P2)+P3 with __fadd_rn; LIF rounding verbatim.

#define TT   128
#define NB   128
#define DD2  1024

// ws layout (u32 units) — identical to R5 (partials/pflag/oflag now unused)
#define SPK0_OFF 0u
#define SPK1_OFF (128u*128u*64u)                 // 1,048,576
#define PART_OFF (2u*128u*128u*64u)              // 2,097,152
#define NHELP    192u
#define FLG_OFF  (PART_OFF + NHELP*4096u)        // 2,883,584
#define NFLG     1536u                           // [unused pflag/oflag] done0 2x128 done1 2x128
#define WS_NEED_BYTES ((size_t)(FLG_OFF + NFLG) * 4u)   // 11,540,480

__device__ __forceinline__ void wait_ge(uint32_t* p, uint32_t tgt){
  while (__hip_atomic_load(p, __ATOMIC_ACQUIRE, __HIP_MEMORY_SCOPE_AGENT) < tgt)
    __builtin_amdgcn_s_sleep(1);
}

// LDS column swizzle for lA: 4-float granules (b128-aligned); constant over a
// 4-aligned k-granule. Spreads staging stores and fma reads across banks.
__device__ __forceinline__ constexpr int fswz(int k){
  return (k & 16) | ((k ^ (k >> 3)) & 12);
}

__global__ void sentinel_kernel(float* o){ o[0] = 42.0f; }   // ws-too-small marker

__global__ __launch_bounds__(512, 2) void snn_kernel(
    const float* __restrict__ x,
    const float* __restrict__ W0, const float* __restrict__ b0,
    const float* __restrict__ W1, const float* __restrict__ b1,
    const float* __restrict__ W2, const float* __restrict__ b2,
    float* __restrict__ out, uint32_t* __restrict__ ws)
{
  __shared__ __align__(16) float lA[2][128][68];   // per-half [k][m^swz], 69,632 B
  __shared__ __align__(16) float lB[2][32][132];   // per-half [n][k],     33,792 B
  __shared__ uint32_t lBits2[2][64];               // per-half spike words

  const int tid  = threadIdx.x;
  const int h    = tid >> 8;       // half: 0/1
  const int t256 = tid & 255;      // R5's tid within the half
  const int tm   = t256 & 15;      // m-group: rows tm*4 .. +3
  const int tn   = t256 >> 4;      // n-group: cols tn*2 .. +1
  const int bid  = blockIdx.x;

  uint32_t* spikes0 = ws + SPK0_OFF;
  uint32_t* spikes1 = ws + SPK1_OFF;
  uint32_t* flg   = ws + FLG_OFF;
  uint32_t* done0 = flg + 1024;     // [2][128] per m-half, target 32
  uint32_t* done1 = flg + 1280;     // [2][128] per m-half, target 64

  int group, tl, m0, n0, K, K0, dTgt;
  const float *Wl, *bl;
  const uint32_t* spkIn; uint32_t* spkOut;
  uint32_t *dIn, *dOut;
  if (bid < 64) {           // L0: halves = two independent tiles, K=1024
    group=0; tl=bid*2+h;
    m0=(tl>>6)*64; n0=(tl&63)*32; K=1024; K0=0; Wl=W0; bl=b0;
    spkIn=nullptr; spkOut=spikes0; dIn=nullptr; dOut=done0+(m0>>6)*128; dTgt=0;
  } else if (bid < 192) {   // L1: halves = k-split halves of one tile
    group=1; tl=bid-64;
    m0=(tl>>6)*64; n0=(tl&63)*32; K=2048; K0=h*1024; Wl=W1; bl=b1;
    spkIn=spikes0; spkOut=spikes1;
    dIn=done0+(m0>>6)*128; dOut=done1+(m0>>6)*128; dTgt=32;
  } else {                  // L2
    group=2; tl=bid-192;
    m0=(tl>>5)*64; n0=(tl&31)*32; K=2048; K0=h*1024; Wl=W2; bl=b2;
    spkIn=spikes1; spkOut=nullptr;
    dIn=done1+(m0>>6)*128; dOut=nullptr; dTgt=64;
  }
  const bool own = (group == 0) || (h == 0);

  const float bias0 = bl[n0 + tn*2 + 0];
  const float bias1 = bl[n0 + tn*2 + 1];

  float vst[4][2];
  #pragma unroll
  for (int r = 0; r < 4; ++r) { vst[r][0] = 0.f; vst[r][1] = 0.f; }

  // spike-expansion mapping (R5 verbatim, on t256)
  const int e_mq   = t256 & 15;     // row quad e_mq*4..+3
  const int e_sub  = t256 >> 4;
  const int e_wsub = e_sub & 3;     // which 32-bit word in chunk
  const int e_kq8  = e_sub >> 2;    // which 8-k octet of that word
  const int e_kloc = e_wsub*32 + e_kq8*8;

  float (*cA)[68]  = lA[h];
  float (*cB)[132] = lB[h];

  for (int t = 0; t < TT; ++t) {
    if (dIn) {  // previous layer's spikes for this m-half must be complete
      if (tid == 0) wait_ge(&dIn[t], (uint32_t)dTgt);
      __syncthreads();
    }

    float acc2[2][4][2];   // two 512-k partial chains (p unrolled -> static idx)
    #pragma unroll
    for (int p = 0; p < 2; ++p)
      #pragma unroll
      for (int r = 0; r < 4; ++r) { acc2[p][r][0] = 0.f; acc2[p][r][1] = 0.f; }

    #pragma unroll
    for (int p = 0; p < 2; ++p) {
      #pragma unroll 1
      for (int ch = 0; ch < 4; ++ch) {            // R5: 4 chunks of 128 k
        const int kb = K0 + p*512 + ch*128;

        // ---- stage B: weights, natural [n][k] layout (contiguous, bank-optimal)
        #pragma unroll
        for (int it = 0; it < 4; ++it) {
          int idx = t256 + it*256;
          int nrow = idx >> 5, kq = idx & 31;
          float4 w = *(const float4*)(Wl + (size_t)(n0+nrow)*K + kb + kq*4);
          *(float4*)&cB[nrow][kq*4] = w;
        }

        // ---- stage A
        if (group == 0) {       // x[b,t,k] -> lA[k][m^swz]
          #pragma unroll
          for (int it = 0; it < 8; ++it) {
            int idx = t256 + it*256;
            int mrow = idx >> 5, kq = idx & 31;
            float4 v = *(const float4*)(x + ((size_t)(m0+mrow)*TT + t)*1024 + kb + kq*4);
            int k0 = kq*4;
            lA[h][k0+0][mrow ^ fswz(k0+0)] = v.x;
            lA[h][k0+1][mrow ^ fswz(k0+1)] = v.y;
            lA[h][k0+2][mrow ^ fswz(k0+2)] = v.z;
            lA[h][k0+3][mrow ^ fswz(k0+3)] = v.w;
          }
        } else {                // spike bits -> {0,1} f32; 4 rows x 8 k per thread
          const size_t rbase = ((size_t)t*NB + m0 + e_mq*4)*64 + (kb>>5) + e_wsub;
          uint32_t w0 = __hip_atomic_load(&spkIn[rbase      ], __ATOMIC_RELAXED, __HIP_MEMORY_SCOPE_AGENT);
          uint32_t w1 = __hip_atomic_load(&spkIn[rbase +  64], __ATOMIC_RELAXED, __HIP_MEMORY_SCOPE_AGENT);
          uint32_t w2 = __hip_atomic_load(&spkIn[rbase + 128], __ATOMIC_RELAXED, __HIP_MEMORY_SCOPE_AGENT);
          uint32_t w3 = __hip_atomic_load(&spkIn[rbase + 192], __ATOMIC_RELAXED, __HIP_MEMORY_SCOPE_AGENT);
          #pragma unroll
          for (int i = 0; i < 8; ++i) {
            int k  = e_kloc + i;
            int sh = k & 31;
            float4 f;
            f.x = ((w0 >> sh) & 1u) ? 1.0f : 0.0f;
            f.y = ((w1 >> sh) & 1u) ? 1.0f : 0.0f;
            f.z = ((w2 >> sh) & 1u) ? 1.0f : 0.0f;
            f.w = ((w3 >> sh) & 1u) ? 1.0f : 0.0f;
            *(float4*)&cA[k][(e_mq*4) ^ fswz(k)] = f;
          }
        }
        __syncthreads();

        // ---- FMA micro-kernel: 128 k x (4m x 2n), sequential ascending k
        #pragma unroll 4
        for (int k4 = 0; k4 < 32; ++k4) {
          const int kbase = k4*4;
          const int sw = fswz(kbase);           // constant over the 4 sub-ks
          const float* pa = &cA[kbase][(tm*4) ^ sw];
          const float4 b0v = *(const float4*)&cB[tn*2    ][kbase];
          const float4 b1v = *(const float4*)&cB[tn*2 + 1][kbase];
          #pragma unroll
          for (int u = 0; u < 4; ++u) {
            const float4 a  = *(const float4*)(pa + u*68);
            const float bv0 = (u==0) ? b0v.x : (u==1) ? b0v.y : (u==2) ? b0v.z : b0v.w;
            const float bv1 = (u==0) ? b1v.x : (u==1) ? b1v.y : (u==2) ? b1v.z : b1v.w;
            acc2[p][0][0] = __builtin_fmaf(a.x, bv0, acc2[p][0][0]);
            acc2[p][1][0] = __builtin_fmaf(a.y, bv0, acc2[p][1][0]);
            acc2[p][2][0] = __builtin_fmaf(a.z, bv0, acc2[p][2][0]);
            acc2[p][3][0] = __builtin_fmaf(a.w, bv0, acc2[p][3][0]);
            acc2[p][0][1] = __builtin_fmaf(a.x, bv1, acc2[p][0][1]);
            acc2[p][1][1] = __builtin_fmaf(a.y, bv1, acc2[p][1][1]);
            acc2[p][2][1] = __builtin_fmaf(a.z, bv1, acc2[p][2][1]);
            acc2[p][3][1] = __builtin_fmaf(a.w, bv1, acc2[p][3][1]);
          }
        }
        __syncthreads();
      }
    }

    // ---- own chains: acc = (P0 + P1), ascending (all threads; helper's dead)
    float acc[4][2];
    #pragma unroll
    for (int r = 0; r < 4; ++r) {
      acc[r][0] = __fadd_rn(acc2[0][r][0], acc2[1][r][0]);
      acc[r][1] = __fadd_rn(acc2[0][r][1], acc2[1][r][1]);
    }

    // ---- k-split exchange via LDS (L1/L2): helper ships P2,P3; owner merges
    if (group != 0) {
      float* ex = &lA[1][0][0];    // helper half's lA, dead until next staging
      if (h == 1) {
        #pragma unroll
        for (int q = 0; q < 4; ++q) {
          const int hh = q >> 1, rb = (q & 1) * 2;
          *(float4*)&ex[t256*16 + q*4] = make_float4(
              acc2[hh][rb+0][0], acc2[hh][rb+0][1],
              acc2[hh][rb+1][0], acc2[hh][rb+1][1]);
        }
      }
      __syncthreads();
      if (h == 0) {   // fold in P2 entirely, then P3 (same order as R5)
        #pragma unroll
        for (int hh = 0; hh < 2; ++hh)
          #pragma unroll
          for (int r = 0; r < 4; ++r) {
            acc[r][0] = __fadd_rn(acc[r][0], ex[t256*16 + hh*8 + r*2 + 0]);
            acc[r][1] = __fadd_rn(acc[r][1], ex[t256*16 + hh*8 + r*2 + 1]);
          }
      }
    }

    if (group < 2) { if (t256 < 64) lBits2[h][t256] = 0; __syncthreads(); }

    // LIF: cur = acc + b (rn); v = 0.9*v + cur (mul+add rn, NO fma contraction);
    // spk = v > 1.0 strictly; v -= spk.  (owners only; L0 = both halves)
    if (own) {
      float sv[4][2], vv8[4][2];
      #pragma unroll
      for (int r = 0; r < 4; ++r) {
        uint32_t msk = 0;
        #pragma unroll
        for (int c = 0; c < 2; ++c) {
          float cur = __fadd_rn(acc[r][c], c ? bias1 : bias0);
          float vv  = __fadd_rn(__fmul_rn(0.9f, vst[r][c]), cur);
          float s   = (vv > 1.0f) ? 1.0f : 0.0f;
          vv = __fsub_rn(vv, s);
          vst[r][c] = vv;
          sv[r][c] = s; vv8[r][c] = vv;
          msk |= (s != 0.f) ? (1u << (tn*2 + c)) : 0u;
        }
        if (group < 2 && msk) atomicOr(&lBits2[h][tm*4 + r], msk);
      }
      if (group == 2) {
        #pragma unroll
        for (int r = 0; r < 4; ++r) {
          size_t o  = ((size_t)(m0 + tm*4 + r)*TT + t)*DD2 + n0 + tn*2;
          *(float2*)(out + o)  = make_float2(sv[r][0], sv[r][1]);
          size_t ov = (size_t)NB*TT*DD2 + o;
          *(float2*)(out + ov) = make_float2(vv8[r][0], vv8[r][1]);
        }
      }
    }

    if (group < 2) {
      __syncthreads();
      if (own && t256 < 64)      // L0: both halves (different words); L1: h==0
        __hip_atomic_store(&spkOut[((size_t)t*NB + m0 + t256)*64 + (n0>>5)],
                           lBits2[h][t256], __ATOMIC_RELAXED, __HIP_MEMORY_SCOPE_AGENT);
      __syncthreads();
      if (tid == 0) __hip_atomic_fetch_add(&dOut[t], 1u, __ATOMIC_RELEASE, __HIP_MEMORY_SCOPE_AGENT);
    }
  }
}

extern "C" void kernel_launch(void* const* d_in, const int* in_sizes, int n_in,
                              void* d_out, int out_size, void* d_ws, size_t ws_size,
                              hipStream_t stream) {
  (void)in_sizes; (void)n_in; (void)out_size;
  float* outf = (float*)d_out;
  if (ws_size < WS_NEED_BYTES) {            // diagnostic: absmax ~41 => ws too small
    sentinel_kernel<<<1, 1, 0, stream>>>(outf);
    return;
  }
  const float* x  = (const float*)d_in[0];
  const float* W0 = (const float*)d_in[1];
  const float* b0 = (const float*)d_in[2];
  const float* W1 = (const float*)d_in[3];
  const float* b1 = (const float*)d_in[4];
  const float* W2 = (const float*)d_in[5];
  const float* b2 = (const float*)d_in[6];
  uint32_t* ws = (uint32_t*)d_ws;

  // zero flags (spikes are write-before-read; done-counters gate everything)
  hipMemsetAsync(ws + FLG_OFF, 0, NFLG * sizeof(uint32_t), stream);

  snn_kernel<<<256, 512, 0, stream>>>(x, W0, b0, W1, b1, W2, b2, outf, ws);
}

// Round 7
// 6312.170 us; speedup vs baseline: 11.7774x; 1.1186x over previous
//
#include <hip/hip_runtime.h>
#include <stdint.h>

// SpikingNetwork B=128 T=128 I=1024 dims 2048/2048/1024, beta=0.9, thr=1.0.
// R11: attack LDS-read throughput (R10's binder: 12288 b128/CU/t ~= 5-8ms on
// the shared LDS pipe vs 1.75ms FMA floor). Thread tile 4m x 2n -> 4m x 4n:
// 8 floats/k for 16 FMA (was 6 for 8) = 1.5x fewer LDS reads per FMA.
// Block tile 64m x 64n, k-chain 512/part: L0 ksplit2 (in-block halves, LDS
// merge), L1/L2 ksplit4 = 2 in-block + R5's proven cross-block pair (odd
// block ships P2,P3 raw via global; owner folds ((P0+P1)+P2)+P3 ascending).
// Grid 256 x 512 unchanged, 1 blk/CU (LDS 137KB), 4 chunks/t (half barriers).
// DAG bit-identical: 512-k ascending fmac chains, __fadd_rn merges in order,
// LIF rounding verbatim. Spikes as bitmasks + done-counters (target 32).

#define TT   128
#define NB   128
#define DD2  1024

// ws layout (u32 units)
#define SPK0_OFF 0u
#define SPK1_OFF (128u*128u*64u)                 // 1,048,576
#define PART_OFF (2u*128u*128u*64u)              // 2,097,152
#define NHELP    96u                             // 96 slots x 8192 floats (32KB)
#define FLG_OFF  (PART_OFF + NHELP*8192u)        // 2,883,584
#define NFLG     1536u                           // pflag512 oflag512 done0 2x128 done1 2x128
#define WS_NEED_BYTES ((size_t)(FLG_OFF + NFLG) * 4u)   // 11,540,480

__device__ __forceinline__ void wait_ge(uint32_t* p, uint32_t tgt){
  while (__hip_atomic_load(p, __ATOMIC_ACQUIRE, __HIP_MEMORY_SCOPE_AGENT) < tgt)
    __builtin_amdgcn_s_sleep(1);
}

// LDS column swizzle for lA: 4-float granules (b128-aligned); constant over a
// 4-aligned k-granule. Spreads staging stores and fma reads across banks.
__device__ __forceinline__ constexpr int fswz(int k){
  return (k & 16) | ((k ^ (k >> 3)) & 12);
}

__global__ void sentinel_kernel(float* o){ o[0] = 42.0f; }   // ws-too-small marker

__global__ __launch_bounds__(512, 2) void snn_kernel(
    const float* __restrict__ x,
    const float* __restrict__ W0, const float* __restrict__ b0,
    const float* __restrict__ W1, const float* __restrict__ b1,
    const float* __restrict__ W2, const float* __restrict__ b2,
    float* __restrict__ out, uint32_t* __restrict__ ws)
{
  __shared__ __align__(16) float lA[2][128][68];   // per-half [k][m^swz], 69,632 B
  __shared__ __align__(16) float lB[2][64][132];   // per-half [n][k],     67,584 B
  __shared__ uint32_t lBits[128];                  // 64 rows x 2 words

  const int tid  = threadIdx.x;
  const int h    = tid >> 8;       // half: 0/1 (k-part within block)
  const int t256 = tid & 255;
  const int tm   = t256 & 15;      // m-group: rows tm*4 .. +3
  const int tn   = t256 >> 4;      // n-group: cols tn*4 .. +3
  const int bid  = blockIdx.x;

  uint32_t* spikes0  = ws + SPK0_OFF;
  uint32_t* spikes1  = ws + SPK1_OFF;
  float*    partials = (float*)(ws + PART_OFF);   // [NHELP][8192]
  uint32_t* flg   = ws + FLG_OFF;
  uint32_t* pflag = flg;            // [512] helper(bid)->owner: partials for t ready
  uint32_t* oflag = flg + 512;      // [512] owner(bid)->helper: consumed through t
  uint32_t* done0 = flg + 1024;     // [2][128] per m-half, target 32
  uint32_t* done1 = flg + 1280;     // [2][128] per m-half, target 32

  int group, pairk, tl, m0, n0, K, hslot;
  const float *Wl, *bl;
  const uint32_t* spkIn; uint32_t* spkOut;
  uint32_t *dIn, *dOut;
  if (bid < 64) {           // L0: 64 tiles 64x64, K=1024, ksplit2 in-block
    group=0; pairk=0; tl=bid;
    m0=(tl>>5)*64; n0=(tl&31)*64; K=1024; Wl=W0; bl=b0;
    spkIn=nullptr; spkOut=spikes0; dIn=nullptr; dOut=done0+(m0>>6)*128; hslot=-1;
  } else if (bid < 192) {   // L1: 64 tiles 64x64, K=2048, ksplit4 (2 blocks/tile)
    group=1; int rel=bid-64; pairk=rel&1; tl=rel>>1;
    m0=(tl>>5)*64; n0=(tl&31)*64; K=2048; Wl=W1; bl=b1;
    spkIn=spikes0; spkOut=spikes1;
    dIn=done0+(m0>>6)*128; dOut=done1+(m0>>6)*128; hslot=tl;
  } else {                  // L2: 32 tiles 64x64, K=2048, ksplit4
    group=2; int rel=bid-192; pairk=rel&1; tl=rel>>1;
    m0=(tl>>4)*64; n0=(tl&15)*64; K=2048; Wl=W2; bl=b2;
    spkIn=spikes1; spkOut=nullptr;
    dIn=done1+(m0>>6)*128; dOut=nullptr; hslot=64+tl;
  }
  const bool helper = (pairk == 1);   // odd block of a pair: ships P2,P3
  const int  K0     = (pairk*2 + h)*512;

  float bias[4];
  #pragma unroll
  for (int c = 0; c < 4; ++c) bias[c] = bl[n0 + tn*4 + c];

  float vst[4][4];   // membrane potential (LIF by owner h=0 threads)
  #pragma unroll
  for (int r = 0; r < 4; ++r)
    #pragma unroll
    for (int c = 0; c < 4; ++c) vst[r][c] = 0.f;

  // spike-expansion mapping (R10 verbatim): 4 rows x 8 k per thread
  const int e_mq   = t256 & 15;
  const int e_sub  = t256 >> 4;
  const int e_wsub = e_sub & 3;
  const int e_kq8  = e_sub >> 2;
  const int e_kloc = e_wsub*32 + e_kq8*8;

  float (*cA)[68]  = lA[h];
  float (*cB)[132] = lB[h];
  float* ex = &lA[1][0][0];   // in-block merge buffer (16KB of helper-half lA)

  for (int t = 0; t < TT; ++t) {
    if (dIn) {  // previous layer's spikes for this m-half must be complete
      if (tid == 0) wait_ge(&dIn[t], 32u);
      __syncthreads();
    }

    float acc[4][4];   // ONE 512-k chain per half
    #pragma unroll
    for (int r = 0; r < 4; ++r)
      #pragma unroll
      for (int c = 0; c < 4; ++c) acc[r][c] = 0.f;

    #pragma unroll 1
    for (int ch = 0; ch < 4; ++ch) {            // 4 chunks of 128 k
      const int kb = K0 + ch*128;

      // ---- stage B: weights, natural [n][k] layout (64 rows x 128 k)
      #pragma unroll
      for (int it = 0; it < 8; ++it) {
        int idx = t256 + it*256;
        int nrow = idx >> 5, kq = idx & 31;
        float4 w = *(const float4*)(Wl + (size_t)(n0+nrow)*K + kb + kq*4);
        *(float4*)&cB[nrow][kq*4] = w;
      }

      // ---- stage A
      if (group == 0) {       // x[b,t,k] -> lA[k][m^swz]
        #pragma unroll
        for (int it = 0; it < 8; ++it) {
          int idx = t256 + it*256;
          int mrow = idx >> 5, kq = idx & 31;
          float4 v = *(const float4*)(x + ((size_t)(m0+mrow)*TT + t)*1024 + kb + kq*4);
          int k0 = kq*4;
          const int sw = fswz(k0);
          const int col = mrow ^ sw;
          cA[k0+0][col] = v.x; cA[k0+1][col] = v.y;
          cA[k0+2][col] = v.z; cA[k0+3][col] = v.w;
        }
      } else {                // spike bits -> {0,1} f32; 4 rows x 8 k per thread
        const size_t rbase = ((size_t)t*NB + m0 + e_mq*4)*64 + (kb>>5) + e_wsub;
        uint32_t w0 = __hip_atomic_load(&spkIn[rbase      ], __ATOMIC_RELAXED, __HIP_MEMORY_SCOPE_AGENT);
        uint32_t w1 = __hip_atomic_load(&spkIn[rbase +  64], __ATOMIC_RELAXED, __HIP_MEMORY_SCOPE_AGENT);
        uint32_t w2 = __hip_atomic_load(&spkIn[rbase + 128], __ATOMIC_RELAXED, __HIP_MEMORY_SCOPE_AGENT);
        uint32_t w3 = __hip_atomic_load(&spkIn[rbase + 192], __ATOMIC_RELAXED, __HIP_MEMORY_SCOPE_AGENT);
        #pragma unroll
        for (int i = 0; i < 8; ++i) {
          int k  = e_kloc + i;
          int sh = k & 31;
          float4 f;
          f.x = ((w0 >> sh) & 1u) ? 1.0f : 0.0f;
          f.y = ((w1 >> sh) & 1u) ? 1.0f : 0.0f;
          f.z = ((w2 >> sh) & 1u) ? 1.0f : 0.0f;
          f.w = ((w3 >> sh) & 1u) ? 1.0f : 0.0f;
          *(float4*)&cA[k][(e_mq*4) ^ fswz(k)] = f;
        }
      }
      __syncthreads();

      // ---- FMA micro-kernel: 128 k x (4m x 4n), sequential ascending k
      #pragma unroll 4
      for (int k4 = 0; k4 < 32; ++k4) {
        const int kbase = k4*4;
        const int sw = fswz(kbase);           // constant over the 4 sub-ks
        const float* pa = &cA[kbase][(tm*4) ^ sw];
        const float4 q0 = *(const float4*)&cB[tn*4+0][kbase];
        const float4 q1 = *(const float4*)&cB[tn*4+1][kbase];
        const float4 q2 = *(const float4*)&cB[tn*4+2][kbase];
        const float4 q3 = *(const float4*)&cB[tn*4+3][kbase];
        #pragma unroll
        for (int u = 0; u < 4; ++u) {
          const float4 a  = *(const float4*)(pa + u*68);
          const float b0v = (u==0) ? q0.x : (u==1) ? q0.y : (u==2) ? q0.z : q0.w;
          const float b1v = (u==0) ? q1.x : (u==1) ? q1.y : (u==2) ? q1.z : q1.w;
          const float b2v = (u==0) ? q2.x : (u==1) ? q2.y : (u==2) ? q2.z : q2.w;
          const float b3v = (u==0) ? q3.x : (u==1) ? q3.y : (u==2) ? q3.z : q3.w;
          acc[0][0] = __builtin_fmaf(a.x, b0v, acc[0][0]);
          acc[1][0] = __builtin_fmaf(a.y, b0v, acc[1][0]);
          acc[2][0] = __builtin_fmaf(a.z, b0v, acc[2][0]);
          acc[3][0] = __builtin_fmaf(a.w, b0v, acc[3][0]);
          acc[0][1] = __builtin_fmaf(a.x, b1v, acc[0][1]);
          acc[1][1] = __builtin_fmaf(a.y, b1v, acc[1][1]);
          acc[2][1] = __builtin_fmaf(a.z, b1v, acc[2][1]);
          acc[3][1] = __builtin_fmaf(a.w, b1v, acc[3][1]);
          acc[0][2] = __builtin_fmaf(a.x, b2v, acc[0][2]);
          acc[1][2] = __builtin_fmaf(a.y, b2v, acc[1][2]);
          acc[2][2] = __builtin_fmaf(a.z, b2v, acc[2][2]);
          acc[3][2] = __builtin_fmaf(a.w, b2v, acc[3][2]);
          acc[0][3] = __builtin_fmaf(a.x, b3v, acc[0][3]);
          acc[1][3] = __builtin_fmaf(a.y, b3v, acc[1][3]);
          acc[2][3] = __builtin_fmaf(a.z, b3v, acc[2][3]);
          acc[3][3] = __builtin_fmaf(a.w, b3v, acc[3][3]);
        }
      }
      __syncthreads();
    }

    if (helper) {
      // ship P2 (h=0) and P3 (h=1) raw; single-buffered vs owner's consumption
      if (t >= 1) { if (tid == 0) wait_ge(&oflag[bid-1], (uint32_t)t); __syncthreads(); }
      uint64_t* pb = (uint64_t*)(partials + (size_t)hslot*8192 + (size_t)h*4096) + t256*8;
      #pragma unroll
      for (int r = 0; r < 4; ++r)
        #pragma unroll
        for (int cq = 0; cq < 2; ++cq) {
          union { float f[2]; uint64_t u; } cv;
          cv.f[0] = acc[r][cq*2+0]; cv.f[1] = acc[r][cq*2+1];
          __hip_atomic_store(&pb[r*2+cq], cv.u, __ATOMIC_RELAXED, __HIP_MEMORY_SCOPE_AGENT);
        }
      __syncthreads();
      if (tid == 0) __hip_atomic_store(&pflag[bid], (uint32_t)(t+1), __ATOMIC_RELEASE, __HIP_MEMORY_SCOPE_AGENT);
      continue;
    }

    // ---- owner in-block merge: acc = P0 + P1 (ascending, __fadd_rn)
    if (h == 1) {
      #pragma unroll
      for (int r = 0; r < 4; ++r)
        *(float4*)&ex[t256*16 + r*4] = make_float4(acc[r][0], acc[r][1], acc[r][2], acc[r][3]);
    }
    __syncthreads();
    if (h == 0) {
      #pragma unroll
      for (int r = 0; r < 4; ++r)
        #pragma unroll
        for (int c = 0; c < 4; ++c)
          acc[r][c] = __fadd_rn(acc[r][c], ex[t256*16 + r*4 + c]);
    }

    // ---- L1/L2: fold helper's P2 entirely, then P3 (same order as R5)
    if (group != 0) {
      if (tid == 0) wait_ge(&pflag[bid+1], (uint32_t)(t+1));
      __syncthreads();
      if (h == 0) {
        uint64_t* p2 = (uint64_t*)(partials + (size_t)hslot*8192) + t256*8;
        uint64_t* p3 = (uint64_t*)(partials + (size_t)hslot*8192 + 4096) + t256*8;
        #pragma unroll
        for (int r = 0; r < 4; ++r)
          #pragma unroll
          for (int cq = 0; cq < 2; ++cq) {
            union { uint64_t u; float f[2]; } cv;
            cv.u = __hip_atomic_load(&p2[r*2+cq], __ATOMIC_RELAXED, __HIP_MEMORY_SCOPE_AGENT);
            acc[r][cq*2+0] = __fadd_rn(acc[r][cq*2+0], cv.f[0]);
            acc[r][cq*2+1] = __fadd_rn(acc[r][cq*2+1], cv.f[1]);
          }
        #pragma unroll
        for (int r = 0; r < 4; ++r)
          #pragma unroll
          for (int cq = 0; cq < 2; ++cq) {
            union { uint64_t u; float f[2]; } cv;
            cv.u = __hip_atomic_load(&p3[r*2+cq], __ATOMIC_RELAXED, __HIP_MEMORY_SCOPE_AGENT);
            acc[r][cq*2+0] = __fadd_rn(acc[r][cq*2+0], cv.f[0]);
            acc[r][cq*2+1] = __fadd_rn(acc[r][cq*2+1], cv.f[1]);
          }
      }
      __syncthreads();
      if (tid == 0) __hip_atomic_store(&oflag[bid], (uint32_t)(t+1), __ATOMIC_RELEASE, __HIP_MEMORY_SCOPE_AGENT);
    }

    if (group < 2) { if (tid < 128) lBits[tid] = 0; __syncthreads(); }

    // LIF: cur = acc + b (rn); v = 0.9*v + cur (mul+add rn, NO fma contraction);
    // spk = v > 1.0 strictly; v -= spk.  (owner h=0 threads hold the full tile)
    if (h == 0) {
      float sv[4][4], vv8[4][4];
      #pragma unroll
      for (int r = 0; r < 4; ++r) {
        uint32_t msk = 0;
        #pragma unroll
        for (int c = 0; c < 4; ++c) {
          float cur = __fadd_rn(acc[r][c], bias[c]);
          float vv  = __fadd_rn(__fmul_rn(0.9f, vst[r][c]), cur);
          float s   = (vv > 1.0f) ? 1.0f : 0.0f;
          vv = __fsub_rn(vv, s);
          vst[r][c] = vv;
          sv[r][c] = s; vv8[r][c] = vv;
          msk |= (s != 0.f) ? (1u << c) : 0u;
        }
        if (group < 2 && msk)
          atomicOr(&lBits[(tm*4 + r)*2 + (tn>>3)], msk << ((tn&7)*4));
      }
      if (group == 2) {
        #pragma unroll
        for (int r = 0; r < 4; ++r) {
          size_t o  = ((size_t)(m0 + tm*4 + r)*TT + t)*DD2 + n0 + tn*4;
          *(float4*)(out + o)  = make_float4(sv[r][0], sv[r][1], sv[r][2], sv[r][3]);
          size_t ov = (size_t)NB*TT*DD2 + o;
          *(float4*)(out + ov) = make_float4(vv8[r][0], vv8[r][1], vv8[r][2], vv8[r][3]);
        }
      }
    }

    if (group < 2) {
      __syncthreads();
      if (tid < 128)
        __hip_atomic_store(&spkOut[((size_t)t*NB + m0 + (tid>>1))*64 + (n0>>5) + (tid&1)],
                           lBits[tid], __ATOMIC_RELAXED, __HIP_MEMORY_SCOPE_AGENT);
      __syncthreads();
      if (tid == 0) __hip_atomic_fetch_add(&dOut[t], 1u, __ATOMIC_RELEASE, __HIP_MEMORY_SCOPE_AGENT);
    }
  }
}

extern "C" void kernel_launch(void* const* d_in, const int* in_sizes, int n_in,
                              void* d_out, int out_size, void* d_ws, size_t ws_size,
                              hipStream_t stream) {
  (void)in_sizes; (void)n_in; (void)out_size;
  float* outf = (float*)d_out;
  if (ws_size < WS_NEED_BYTES) {            // diagnostic: absmax ~41 => ws too small
    sentinel_kernel<<<1, 1, 0, stream>>>(outf);
    return;
  }
  const float* x  = (const float*)d_in[0];
  const float* W0 = (const float*)d_in[1];
  const float* b0 = (const float*)d_in[2];
  const float* W1 = (const float*)d_in[3];
  const float* b1 = (const float*)d_in[4];
  const float* W2 = (const float*)d_in[5];
  const float* b2 = (const float*)d_in[6];
  uint32_t* ws = (uint32_t*)d_ws;

  // zero flags (spikes/partials are write-before-read; flags gate everything)
  hipMemsetAsync(ws + FLG_OFF, 0, NFLG * sizeof(uint32_t), stream);

  snn_kernel<<<256, 512, 0, stream>>>(x, W0, b0, W1, b1, W2, b2, outf, ws);
}